// Round 3
// baseline (248.739 us; speedup 1.0000x reference)
//
#include <hip/hip_runtime.h>

// ConvexSampler: out = [ concat(z, s*z[a]+(1-s)*z[b]) ; labels(+oos) ; data_type(+1.0) ]
// B=16384, D=2048, NCONV=50. Memory-bound; v3 = v2 with clang-native float4
// (ext_vector_type) so __builtin_nontemporal_store compiles.

#define B_ROWS 16384
#define D_COLS 2048
#define NCONV  50
#define D4     (D_COLS / 4)        // 512 float4 per row
#define NZ4    (B_ROWS * D4)       // 8,388,608 float4 bulk-copy items
#define NC4    (NCONV * D4)        //    25,600 convex float4 items
#define NR     (B_ROWS + NCONV)    //    16,434 output rows
#define NTAIL  (2 * NR)            //    32,868 scalar tail items

#define IPT          16                         // float4 per thread (MLP depth)
#define COPY_BLOCKS  (NZ4 / (256 * IPT))        // 2048 exact
#define CONV_BLOCKS  ((NC4 + 255) / 256)        // 100 exact
#define TAIL_BLOCKS  ((NTAIL + 255) / 256)      // 129

typedef float f4 __attribute__((ext_vector_type(4)));  // clang-native vec4

__global__ __launch_bounds__(256) void convex_sampler_v3(
    const float* __restrict__ z,
    const int*   __restrict__ label_ids,
    const float* __restrict__ data_type,
    const int*   __restrict__ pair_idx,
    const float* __restrict__ s,
    const int*   __restrict__ oos_label_id,
    float*       __restrict__ out)
{
    const f4* __restrict__ z4   = (const f4*)z;
    f4*       __restrict__ out4 = (f4*)out;

    const int bid = blockIdx.x;

    if (bid < COPY_BLOCKS) {
        // ---- Bulk copy: 16 independent 16B loads in flight, then 16 stores.
        // Block covers a contiguous 4096-float4 (64 KiB) chunk; per k the 256
        // lanes are contiguous -> perfectly coalesced.
        const int base = bid * (256 * IPT) + threadIdx.x;
        f4 v[IPT];
        #pragma unroll
        for (int k = 0; k < IPT; ++k)
            v[k] = z4[base + k * 256];
        #pragma unroll
        for (int k = 0; k < IPT; ++k)
            __builtin_nontemporal_store(v[k], &out4[base + k * 256]);
        return;
    }

    if (bid < COPY_BLOCKS + CONV_BLOCKS) {
        // ---- Convex rows: out row (B+r) = s[r]*z[a] + (1-s[r])*z[b].
        // 25,600 float4 items exactly; z rows re-read here hit L2/L3.
        const int j  = (bid - COPY_BLOCKS) * 256 + threadIdx.x;  // 0..25599
        const int r  = j >> 9;        // /512 -> convex row
        const int c4 = j & 511;       // float4 column
        const int ia = pair_idx[2 * r];
        const int ib = pair_idx[2 * r + 1];
        const float sv = s[r];
        const float tv = 1.0f - sv;
        const f4 a = z4[ia * D4 + c4];
        const f4 b = z4[ib * D4 + c4];
        f4 rr;
        rr.x = sv * a.x + tv * b.x;
        rr.y = sv * a.y + tv * b.y;
        rr.z = sv * a.z + tv * b.z;
        rr.w = sv * a.w + tv * b.w;
        out4[NZ4 + j] = rr;
        return;
    }

    // ---- Scalar tails: labels_out then data_type_out, after (B+50)*D floats.
    {
        const int t = (bid - COPY_BLOCKS - CONV_BLOCKS) * 256 + threadIdx.x;
        if (t >= NTAIL) return;
        const int base = NR * D_COLS;   // 33,656,832
        if (t < NR) {
            float v = (t < B_ROWS) ? (float)label_ids[t]
                                   : (float)(*oos_label_id);
            out[base + t] = v;
        } else {
            const int u = t - NR;
            float v = (u < B_ROWS) ? data_type[u] : 1.0f;
            out[base + NR + u] = v;
        }
    }
}

extern "C" void kernel_launch(void* const* d_in, const int* in_sizes, int n_in,
                              void* d_out, int out_size, void* d_ws, size_t ws_size,
                              hipStream_t stream) {
    const float* z          = (const float*)d_in[0];
    const int*   label_ids  = (const int*)  d_in[1];
    const float* data_type  = (const float*)d_in[2];
    const int*   pair_idx   = (const int*)  d_in[3];
    const float* s          = (const float*)d_in[4];
    const int*   oos        = (const int*)  d_in[5];
    float*       out        = (float*)d_out;

    dim3 grid(COPY_BLOCKS + CONV_BLOCKS + TAIL_BLOCKS), block(256);
    hipLaunchKernelGGL(convex_sampler_v3, grid, block, 0, stream,
                       z, label_ids, data_type, pair_idx, s, oos, out);
}

// Round 4
// 240.962 us; speedup vs baseline: 1.0323x; 1.0323x over previous
//
#include <hip/hip_runtime.h>

// ConvexSampler v4 — diagnostic split: two half-copies (to detect poison-drain
// interference decaying over time) + one small kernel for convex rows & tails.
// Regular (cache-allocating) stores: overwrite the harness's 0xAA poison lines
// in-cache instead of forcing them + us to HBM separately.

#define B_ROWS 16384
#define D_COLS 2048
#define NCONV  50
#define D4     (D_COLS / 4)        // 512 float4 per row
#define NZ4    (B_ROWS * D4)       // 8,388,608 float4 total copy items
#define HALF4  (NZ4 / 2)           // 4,194,304 per half
#define NC4    (NCONV * D4)        // 25,600 convex float4 items
#define NR     (B_ROWS + NCONV)    // 16,434 output rows
#define NTAIL  (2 * NR)            // 32,868 scalar tail items

#define IPT        8
#define COPY_BLKS  (HALF4 / (256 * IPT))      // 2048 exact
#define CONV_BLKS  ((NC4 + 255) / 256)        // 100 exact
#define TAIL_BLKS  ((NTAIL + 255) / 256)      // 129
#define SMALL_BLKS (CONV_BLKS + TAIL_BLKS)    // 229

typedef float f4 __attribute__((ext_vector_type(4)));

__global__ __launch_bounds__(256) void copy_half(const f4* __restrict__ src,
                                                 f4* __restrict__ dst)
{
    // 8 independent 16B loads in flight, then 8 cache-allocating stores.
    const int base = blockIdx.x * (256 * IPT) + threadIdx.x;
    f4 v[IPT];
    #pragma unroll
    for (int k = 0; k < IPT; ++k)
        v[k] = src[base + k * 256];
    #pragma unroll
    for (int k = 0; k < IPT; ++k)
        dst[base + k * 256] = v[k];
}

__global__ __launch_bounds__(256) void convex_and_tails(
    const float* __restrict__ z,
    const int*   __restrict__ label_ids,
    const float* __restrict__ data_type,
    const int*   __restrict__ pair_idx,
    const float* __restrict__ s,
    const int*   __restrict__ oos_label_id,
    float*       __restrict__ out)
{
    const f4* __restrict__ z4   = (const f4*)z;
    f4*       __restrict__ out4 = (f4*)out;
    const int bid = blockIdx.x;

    if (bid < CONV_BLKS) {
        // Convex rows: out row (B+r) = s[r]*z[a] + (1-s[r])*z[b]
        const int j  = bid * 256 + threadIdx.x;   // 0..25599
        const int r  = j >> 9;
        const int c4 = j & 511;
        const int ia = pair_idx[2 * r];
        const int ib = pair_idx[2 * r + 1];
        const float sv = s[r];
        const float tv = 1.0f - sv;
        const f4 a = z4[ia * D4 + c4];
        const f4 b = z4[ib * D4 + c4];
        f4 rr;
        rr.x = sv * a.x + tv * b.x;
        rr.y = sv * a.y + tv * b.y;
        rr.z = sv * a.z + tv * b.z;
        rr.w = sv * a.w + tv * b.w;
        out4[NZ4 + j] = rr;
        return;
    }

    // Scalar tails: labels_out then data_type_out, after (B+50)*D floats.
    const int t = (bid - CONV_BLKS) * 256 + threadIdx.x;
    if (t >= NTAIL) return;
    const int base = NR * D_COLS;   // 33,656,832
    if (t < NR) {
        float v = (t < B_ROWS) ? (float)label_ids[t]
                               : (float)(*oos_label_id);
        out[base + t] = v;
    } else {
        const int u = t - NR;
        float v = (u < B_ROWS) ? data_type[u] : 1.0f;
        out[base + NR + u] = v;
    }
}

extern "C" void kernel_launch(void* const* d_in, const int* in_sizes, int n_in,
                              void* d_out, int out_size, void* d_ws, size_t ws_size,
                              hipStream_t stream) {
    const float* z          = (const float*)d_in[0];
    const int*   label_ids  = (const int*)  d_in[1];
    const float* data_type  = (const float*)d_in[2];
    const int*   pair_idx   = (const int*)  d_in[3];
    const float* s          = (const float*)d_in[4];
    const int*   oos        = (const int*)  d_in[5];
    float*       out        = (float*)d_out;

    const f4* z4   = (const f4*)z;
    f4*       out4 = (f4*)out;

    hipLaunchKernelGGL(copy_half, dim3(COPY_BLKS), dim3(256), 0, stream,
                       z4, out4);                          // first half
    hipLaunchKernelGGL(copy_half, dim3(COPY_BLKS), dim3(256), 0, stream,
                       z4 + HALF4, out4 + HALF4);          // second half
    hipLaunchKernelGGL(convex_and_tails, dim3(SMALL_BLKS), dim3(256), 0, stream,
                       z, label_ids, data_type, pair_idx, s, oos, out);
}

// Round 6
// 228.907 us; speedup vs baseline: 1.0866x; 1.0527x over previous
//
#include <hip/hip_runtime.h>

// ConvexSampler v5 — full cache-bypass probe: nontemporal loads AND stores on
// the bulk copy so our kernel allocates nothing in L2/L3. Tests whether the
// harness poison-fill's lazy writeback (eviction-driven) is what throttles our
// window to ~2.4 TB/s. Convex rows + tails stay cache-normal (tiny).
// (Resubmitted unchanged: Round 5 died on GPU acquisition, no data.)

#define B_ROWS 16384
#define D_COLS 2048
#define NCONV  50
#define D4     (D_COLS / 4)        // 512 float4 per row
#define NZ4    (B_ROWS * D4)       // 8,388,608 float4 bulk-copy items
#define NC4    (NCONV * D4)        // 25,600 convex float4 items
#define NR     (B_ROWS + NCONV)    // 16,434 output rows
#define NTAIL  (2 * NR)            // 32,868 scalar tail items

#define IPT        8
#define COPY_BLKS  (NZ4 / (256 * IPT))        // 4096 exact
#define CONV_BLKS  ((NC4 + 255) / 256)        // 100 exact
#define TAIL_BLKS  ((NTAIL + 255) / 256)      // 129

typedef float f4 __attribute__((ext_vector_type(4)));

__global__ __launch_bounds__(256) void convex_sampler_v5(
    const float* __restrict__ z,
    const int*   __restrict__ label_ids,
    const float* __restrict__ data_type,
    const int*   __restrict__ pair_idx,
    const float* __restrict__ s,
    const int*   __restrict__ oos_label_id,
    float*       __restrict__ out)
{
    const f4* __restrict__ z4   = (const f4*)z;
    f4*       __restrict__ out4 = (f4*)out;
    const int bid = blockIdx.x;

    if (bid < COPY_BLKS) {
        // Bulk copy, fully bypassing cache allocation on both sides.
        const int base = bid * (256 * IPT) + threadIdx.x;
        f4 v[IPT];
        #pragma unroll
        for (int k = 0; k < IPT; ++k)
            v[k] = __builtin_nontemporal_load(&z4[base + k * 256]);
        #pragma unroll
        for (int k = 0; k < IPT; ++k)
            __builtin_nontemporal_store(v[k], &out4[base + k * 256]);
        return;
    }

    if (bid < COPY_BLKS + CONV_BLKS) {
        // Convex rows: out row (B+r) = s[r]*z[a] + (1-s[r])*z[b]
        const int j  = (bid - COPY_BLKS) * 256 + threadIdx.x;   // 0..25599
        const int r  = j >> 9;
        const int c4 = j & 511;
        const int ia = pair_idx[2 * r];
        const int ib = pair_idx[2 * r + 1];
        const float sv = s[r];
        const float tv = 1.0f - sv;
        const f4 a = z4[ia * D4 + c4];
        const f4 b = z4[ib * D4 + c4];
        f4 rr;
        rr.x = sv * a.x + tv * b.x;
        rr.y = sv * a.y + tv * b.y;
        rr.z = sv * a.z + tv * b.z;
        rr.w = sv * a.w + tv * b.w;
        out4[NZ4 + j] = rr;
        return;
    }

    // Scalar tails: labels_out then data_type_out, after (B+50)*D floats.
    const int t = (bid - COPY_BLKS - CONV_BLKS) * 256 + threadIdx.x;
    if (t >= NTAIL) return;
    const int base = NR * D_COLS;   // 33,656,832
    if (t < NR) {
        float v = (t < B_ROWS) ? (float)label_ids[t]
                               : (float)(*oos_label_id);
        out[base + t] = v;
    } else {
        const int u = t - NR;
        float v = (u < B_ROWS) ? data_type[u] : 1.0f;
        out[base + NR + u] = v;
    }
}

extern "C" void kernel_launch(void* const* d_in, const int* in_sizes, int n_in,
                              void* d_out, int out_size, void* d_ws, size_t ws_size,
                              hipStream_t stream) {
    const float* z          = (const float*)d_in[0];
    const int*   label_ids  = (const int*)  d_in[1];
    const float* data_type  = (const float*)d_in[2];
    const int*   pair_idx   = (const int*)  d_in[3];
    const float* s          = (const float*)d_in[4];
    const int*   oos        = (const int*)  d_in[5];
    float*       out        = (float*)d_out;

    dim3 grid(COPY_BLKS + CONV_BLKS + TAIL_BLKS), block(256);
    hipLaunchKernelGGL(convex_sampler_v5, grid, block, 0, stream,
                       z, label_ids, data_type, pair_idx, s, oos, out);
}